// Round 2
// baseline (91.155 us; speedup 1.0000x reference)
//
#include <hip/hip_runtime.h>

namespace {
constexpr int NA  = 128;
constexpr int NC2 = NA * (NA - 1) / 2;           // 8128
constexpr float SCALE = 627.5095f * 0.529177f / 100.0f;  // AU2KCALMOLA / MAX_NRF
}

// One block per batch row; lane <-> single pair (p = iter*256 + tid).
// Consecutive lanes have consecutive pair indices, so:
//   - c4[j] LDS reads are stride-16B across lanes -> conflict-free full-BW
//   - c4[i] LDS reads are near-uniform across a wave -> broadcast (free)
//   - atoms[p] global loads and out[p] stores are perfectly coalesced
// (i,j) from p via f32 sqrt (exact to +-1 for p<8128) + branchless 2-sided
// fixup: tri(i)=i(i-1)/2, tri(i-1)=tri(i)-(i-1), tri(i+1)=tri(i)+i.
__global__ __launch_bounds__(256) void nrf_kernel(
    const float* __restrict__ coords,
    const float* __restrict__ atoms,
    float* __restrict__ out)
{
    __shared__ float4 c4[NA];
    const int b   = blockIdx.x;
    const int tid = threadIdx.x;

    // Stage coords[b] (384 contiguous floats) -> AoS float4 (x,y,z,pad).
    const float* cb = coords + (size_t)b * (NA * 3);
    for (int k = tid; k < NA * 3; k += 256) {
        int atom = k / 3;                 // constant div -> magic mul
        int comp = k - atom * 3;
        reinterpret_cast<float*>(&c4[atom])[comp] = cb[k];
    }
    __syncthreads();

    float* outb = out + (size_t)b * NC2;

    for (int p = tid; p < NC2; p += 256) {
        // row index: i = floor((1+sqrt(8p+1))/2), then +-1 branchless fixup
        int i = (int)((1.0f + sqrtf((float)(8 * p + 1))) * 0.5f);
        int t = (i * (i - 1)) >> 1;       // tri(i)
        bool hi = (t > p);                // overshoot -> step down
        i -= hi;
        t -= hi ? i : 0;                  // tri(i-1) = tri(i) - new_i
        bool lo = (t + i <= p);           // undershoot -> step up
        t += lo ? i : 0;                  // tri(i+1) = tri(i) + old_i
        i += lo;
        int j = p - t;

        float4 ci = c4[i];                // near-uniform -> LDS broadcast
        float4 cj = c4[j];                // lane-consecutive -> conflict-free
        float dx = ci.x - cj.x;
        float dy = ci.y - cj.y;
        float dz = ci.z - cj.z;
        float d2 = dx * dx + dy * dy + dz * dz;
        // ref computes 1/(sqrt(d2))^2 == 1/d2 within ~2 ulp; rcp is 1 ulp
        outb[p] = atoms[p] * SCALE * __builtin_amdgcn_rcpf(d2);
    }
}

extern "C" void kernel_launch(void* const* d_in, const int* in_sizes, int n_in,
                              void* d_out, int out_size, void* d_ws, size_t ws_size,
                              hipStream_t stream)
{
    const float* coords = (const float*)d_in[0];
    const float* atoms  = (const float*)d_in[1];
    float*       out    = (float*)d_out;
    const int batch = in_sizes[0] / (NA * 3);    // 2048
    nrf_kernel<<<batch, 256, 0, stream>>>(coords, atoms, out);
}

// Round 3
// 82.323 us; speedup vs baseline: 1.1073x; 1.1073x over previous
//
#include <hip/hip_runtime.h>

namespace {
constexpr int NA  = 128;
constexpr int NC2 = NA * (NA - 1) / 2;           // 8128
constexpr int R   = 4;                           // batch rows per block
constexpr float SCALE = 627.5095f * 0.529177f / 100.0f;  // AU2KCALMOLA / MAX_NRF
}

// Triangle packing: pair-slot q in [0, NC2). Chunk u = q>>7 (128 slots)
// covers row a=u+1 (slots r<a -> pair (a,r)) and row b=127-u (slots r>=a ->
// pair (b, r-a)); a+b=128 exactly, so packing is waste-free and index math
// is ~10 int ops (no sqrt, no loops). Within a wave, i takes at most 2
// values -> LDS broadcast (free); j is consecutive per segment -> conflict-
// free ds_read_b128. Output position p = tri(i)+j gives 2 contiguous store
// segments per 128-slot chunk -> still coalesced.
// Each block handles R=4 batch rows: index math + atoms[p]*SCALE computed
// once, reused for 4 rows (4x less index VALU, 4x less atoms L2 traffic).
__global__ __launch_bounds__(512) void nrf_kernel(
    const float* __restrict__ coords,
    const float* __restrict__ atoms,
    float* __restrict__ out)
{
    __shared__ float4 c4[R][NA];
    const int b0  = blockIdx.x * R;
    const int tid = threadIdx.x;

    // Stage R rows (R*NA*3 contiguous floats) -> AoS float4 (x,y,z,pad).
    const float* cb = coords + (size_t)b0 * (NA * 3);
    float* c4f = reinterpret_cast<float*>(&c4[0][0]);
    for (int k = tid; k < R * NA * 3; k += 512) {
        int atom = k / 3;                 // constant div -> magic mul
        int comp = k - atom * 3;
        c4f[atom * 4 + comp] = cb[k];     // c4 is row-major, matches flat atom
    }
    __syncthreads();

    float* outb = out + (size_t)b0 * NC2;

    for (int q = tid; q < NC2; q += 512) {
        int u = q >> 7;
        int r = q & 127;
        int a = u + 1;
        bool lo = (r < a);
        int i = lo ? a : 127 - u;
        int j = lo ? r : r - a;
        int p = ((i * (i - 1)) >> 1) + j;

        float av = atoms[p] * SCALE;      // once per R rows

        float* o = outb + p;
        #pragma unroll
        for (int m = 0; m < R; ++m) {
            float4 ci = c4[m][i];         // <=2 distinct values/wave -> bcast
            float4 cj = c4[m][j];         // lane-consecutive -> conflict-free
            float dx = ci.x - cj.x;
            float dy = ci.y - cj.y;
            float dz = ci.z - cj.z;
            float d2 = dx * dx + dy * dy + dz * dz;
            // ref: 1/(sqrt(d2))^2 == 1/d2 within ~2 ulp; v_rcp_f32 is 1 ulp
            o[(size_t)m * NC2] = av * __builtin_amdgcn_rcpf(d2);
        }
    }
}

extern "C" void kernel_launch(void* const* d_in, const int* in_sizes, int n_in,
                              void* d_out, int out_size, void* d_ws, size_t ws_size,
                              hipStream_t stream)
{
    const float* coords = (const float*)d_in[0];
    const float* atoms  = (const float*)d_in[1];
    float*       out    = (float*)d_out;
    const int batch = in_sizes[0] / (NA * 3);    // 2048
    nrf_kernel<<<batch / R, 512, 0, stream>>>(coords, atoms, out);
}